// Round 7
// baseline (163.384 us; speedup 1.0000x reference)
//
#include <hip/hip_runtime.h>

typedef _Float16 half8 __attribute__((ext_vector_type(8)));
typedef float floatx4 __attribute__((ext_vector_type(4)));

constexpr int C  = 32, H = 512, W = 512, HW = H * W;
constexpr int Hp = 514, Wp = 514;               // padded (1-px halo)
constexpr int NPX = 2 * Hp * Wp;                // padded pixels, both batches

// ws layout (bytes): x_pack (padded NHWC fp16) | d_pack (float2 em,ep) | w_pack
constexpr size_t XOFF = 0;
constexpr size_t XSZ  = (size_t)NPX * 64;        // 32 ch * 2 B
constexpr size_t DOFF = XOFF + XSZ;
constexpr size_t DSZ  = (size_t)NPX * 8;
constexpr size_t WOFF = DOFF + DSZ;
// total required: ~38.1 MB <= ws_size (validated in Round 5)

constexpr int PITCH = 258;                       // LDS row pitch (floats): 2-way-free readback

__device__ __forceinline__ unsigned pack2h(float lo, float hi) {
    unsigned a = (unsigned)__builtin_bit_cast(unsigned short, (_Float16)lo);
    unsigned b = (unsigned)__builtin_bit_cast(unsigned short, (_Float16)hi);
    return a | (b << 16);
}

// ---- ONE pack kernel:
//  blocks [0,2048): x NCHW fp32 -> padded NHWC fp16. Block = 1 row x 256 px x 32 ch:
//                   per-channel reads are 1 KB CONTIGUOUS (DRAM-friendly granule),
//                   LDS transpose, fused depth->(exp(-8.3d),exp(+8.3d)).
//  blocks [2048,2065): zero the 1-px halo border (border taps -> exact 0)
//  blocks [2065,2070): weights -> per-lane fp16 A-fragment uint4s
__global__ __launch_bounds__(256) void pack_all(
    const float* __restrict__ x, const float* __restrict__ depth,
    const float* __restrict__ weight,
    unsigned* __restrict__ xp, float2* __restrict__ dpk, uint4* __restrict__ wp)
{
    const int bid = blockIdx.x;
    const int tid = threadIdx.x;

    if (bid >= 2048) {
        if (bid < 2065) {                        // ---- border zero
            int i = (bid - 2048) * 256 + tid;
            if (i >= 4104) return;               // 2 * (2*514 + 2*512)
            int b = i / 2052, r = i % 2052;
            int hh, ww;
            if (r < 514)       { hh = 0;   ww = r; }
            else if (r < 1028) { hh = 513; ww = r - 514; }
            else { int j = r - 1028; hh = 1 + (j >> 1); ww = (j & 1) ? 513 : 0; }
            size_t ppx = ((size_t)(b * Hp + hh)) * Wp + ww;
            uint4 z = {0u, 0u, 0u, 0u};
            uint4* p = (uint4*)(xp + ppx * 16);
            p[0] = z; p[1] = z; p[2] = z; p[3] = z;
            dpk[ppx] = make_float2(0.f, 0.f);
        } else {                                 // ---- weight pack (fp16 A-frags)
            int j = (bid - 2065) * 256 + tid;
            if (j >= 1152) return;               // 9 taps * 2 halves * 64 lanes
            int lane = j & 63, half = (j >> 6) & 1, tap = j >> 7;
            int o = half * 16 + (lane & 15), q = lane >> 4;
            uint4 v;
            v.x = pack2h(weight[(o * 32 + q * 8 + 0) * 9 + tap], weight[(o * 32 + q * 8 + 1) * 9 + tap]);
            v.y = pack2h(weight[(o * 32 + q * 8 + 2) * 9 + tap], weight[(o * 32 + q * 8 + 3) * 9 + tap]);
            v.z = pack2h(weight[(o * 32 + q * 8 + 4) * 9 + tap], weight[(o * 32 + q * 8 + 5) * 9 + tap]);
            v.w = pack2h(weight[(o * 32 + q * 8 + 6) * 9 + tap], weight[(o * 32 + q * 8 + 7) * 9 + tap]);
            wp[j] = v;
        }
        return;
    }

    // ---- x transpose: 1 row x 256 px x 32 channels per block
    __shared__ float t[32][PITCH];
    const int halfrow = bid & 1, h = (bid >> 1) & 511, b = bid >> 10;
    const int px0 = halfrow * 256;

    const float* xb = x + (size_t)b * C * HW + h * W + px0;
    const int c = tid >> 3, f = tid & 7;         // 8 threads per channel
    float4 v[8];
    #pragma unroll
    for (int i = 0; i < 8; ++i)                  // per channel: 8x16B spanning 1 KB contiguous
        v[i] = *(const float4*)(xb + (size_t)c * HW + (f + 8 * i) * 4);
    #pragma unroll
    for (int i = 0; i < 8; ++i) {
        int px = (f + 8 * i) * 4;
        *(float2*)&t[c][px]     = make_float2(v[i].x, v[i].y);
        *(float2*)&t[c][px + 2] = make_float2(v[i].z, v[i].w);
    }

    // fused depth pack (no LDS dependence): one px per thread
    {
        float d = depth[(size_t)b * HW + h * W + px0 + tid];
        size_t ppx = ((size_t)(b * Hp + h + 1)) * Wp + (px0 + 1 + tid);
        dpk[ppx] = make_float2(__expf(-8.3f * d), __expf(8.3f * d));
    }
    __syncthreads();

    // readback columns -> packed NHWC uint4 (2-way bank alias, free)
    const int q = tid & 3;
    #pragma unroll
    for (int r = 0; r < 4; ++r) {
        int px = r * 64 + (tid >> 2);
        uint4 o;
        o.x = pack2h(t[q * 8 + 0][px], t[q * 8 + 1][px]);
        o.y = pack2h(t[q * 8 + 2][px], t[q * 8 + 3][px]);
        o.z = pack2h(t[q * 8 + 4][px], t[q * 8 + 5][px]);
        o.w = pack2h(t[q * 8 + 6][px], t[q * 8 + 7][px]);
        size_t ppx = ((size_t)(b * Hp + h + 1)) * Wp + (px0 + 1 + px);
        *(uint4*)(xp + ppx * 16 + q * 4) = o;
    }
}

// ---- main conv: ALL 9 xp + 9 dpk loads issued upfront into registers
// (independent, in flight together) -> latency paid once, not 9x serially.
__global__ __launch_bounds__(256) void depthconv_main(
    const unsigned* __restrict__ xp,
    const float2*   __restrict__ dpk,
    const uint4*    __restrict__ wp,
    const float*    __restrict__ bias,
    float*          __restrict__ out)
{
    const int bid  = blockIdx.x;                 // b(2) x h(512) x wseg(8)
    const int wseg = bid & 7, h = (bid >> 3) & 511, b = bid >> 12;
    const int lane = threadIdx.x & 63, wid = threadIdx.x >> 6;
    const int nn   = lane & 15, q = lane >> 4;
    const int pw   = wseg * 64 + wid * 16 + nn;  // output column 0..511

    const size_t rowbase = ((size_t)(b * Hp + h)) * Wp + pw;  // padded (h+ki, pw+kj)

    // ---- issue ALL tap loads upfront (18 independent VMEM ops in flight)
    uint4  xv[9];
    float2 dn[9];
    #pragma unroll
    for (int ki = 0; ki < 3; ++ki) {
        #pragma unroll
        for (int kj = 0; kj < 3; ++kj) {
            const int tap = ki * 3 + kj;
            const size_t np = rowbase + (size_t)ki * Wp + kj;
            xv[tap] = *(const uint4*)(xp + np * 16 + q * 4);
            dn[tap] = dpk[np];
        }
    }

    floatx4 acc0, acc1;                          // C/D: col=nn, row(o)=4q+reg
    #pragma unroll
    for (int r = 0; r < 4; ++r) {
        acc0[r] = bias[q * 4 + r];
        acc1[r] = bias[16 + q * 4 + r];
    }

    const float2 dc = dn[4];                     // center pixel == tap 4

    #pragma unroll
    for (int tap = 0; tap < 9; ++tap) {
        float s = (tap == 4) ? 1.0f
                             : fminf(dn[tap].y * dc.x, dn[tap].x * dc.y);  // exp(-8.3|dc-dn|)
        _Float16 hs = (_Float16)s;
        half8 sv = { hs, hs, hs, hs, hs, hs, hs, hs };
        half8 bfrag = __builtin_bit_cast(half8, xv[tap]) * sv;   // 4x v_pk_mul_f16

        half8 af0 = __builtin_bit_cast(half8, wp[(tap * 2 + 0) * 64 + lane]); // L1-hot
        half8 af1 = __builtin_bit_cast(half8, wp[(tap * 2 + 1) * 64 + lane]);

        acc0 = __builtin_amdgcn_mfma_f32_16x16x32_f16(af0, bfrag, acc0, 0, 0, 0);
        acc1 = __builtin_amdgcn_mfma_f32_16x16x32_f16(af1, bfrag, acc1, 0, 0, 0);
    }

    float* op = out + (size_t)b * C * HW + h * W + pw;
    #pragma unroll
    for (int r = 0; r < 4; ++r) {                // nontemporal: out never re-read
        __builtin_nontemporal_store(acc0[r], op + (size_t)(q * 4 + r) * HW);
        __builtin_nontemporal_store(acc1[r], op + (size_t)(16 + q * 4 + r) * HW);
    }
}

extern "C" void kernel_launch(void* const* d_in, const int* in_sizes, int n_in,
                              void* d_out, int out_size, void* d_ws, size_t ws_size,
                              hipStream_t stream) {
    const float* x      = (const float*)d_in[0];
    const float* depth  = (const float*)d_in[1];
    const float* weight = (const float*)d_in[2];
    const float* bias   = (const float*)d_in[3];
    float* out          = (float*)d_out;

    unsigned* xp  = (unsigned*)((char*)d_ws + XOFF);
    float2*   dpk = (float2*)  ((char*)d_ws + DOFF);
    uint4*    wpk = (uint4*)   ((char*)d_ws + WOFF);

    hipLaunchKernelGGL(pack_all, dim3(2070), dim3(256), 0, stream,
                       x, depth, weight, xp, dpk, wpk);
    hipLaunchKernelGGL(depthconv_main, dim3(2 * 512 * 8), dim3(256), 0, stream,
                       xp, dpk, wpk, bias, out);
}